// Round 7
// baseline (320.393 us; speedup 1.0000x reference)
//
#include <hip/hip_runtime.h>
#include <hip/hip_bf16.h>

namespace {

typedef __attribute__((ext_vector_type(8))) short bf16x8;   // 8 bf16 = 4 VGPRs
typedef __attribute__((ext_vector_type(4))) float f32x4;
typedef __attribute__((ext_vector_type(4))) unsigned u32x4v;

constexpr int BATCH = 4;
constexpr int SEQ   = 2048;
constexpr int EMB   = 1024;
constexpr int NH    = 16;
constexpr int HD    = 64;
constexpr int MTOT  = BATCH * SEQ;           // 8192
constexpr float LOG2E = 1.44269504088896f;
constexpr float SOFTMAX_C = 16.0f;           // static max substitute (log2 units)

__device__ __forceinline__ unsigned short f2bf(float x) {
    unsigned int u = __float_as_uint(x);
    u += 0x7fffu + ((u >> 16) & 1u);         // round-to-nearest-even
    return (unsigned short)(u >> 16);
}

// async global->LDS, 16B per lane; LDS dest must be wave-uniform base + lane*16
__device__ __forceinline__ void gl_lds16(const void* g, void* l) {
    __builtin_amdgcn_global_load_lds(
        (const __attribute__((address_space(1))) unsigned int*)g,
        (__attribute__((address_space(3))) unsigned int*)l, 16, 0, 0);
}

// ---------------------------------------------------------------------------
// Fused preprocessing, flat 1D grid (no idle blocks):
//   bid <  16384 : fp32->bf16 conv of dec (bid<8192) / enc
//   bid >= 16384 : 1024 weight-transpose blocks (4 weights x 16x16 tiles)
// ---------------------------------------------------------------------------
__global__ __launch_bounds__(256)
void prep(const float* __restrict__ dec, const float* __restrict__ enc,
          unsigned short* __restrict__ decb, unsigned short* __restrict__ encb,
          const float* __restrict__ W0, const float* __restrict__ W1,
          const float* __restrict__ W2, const float* __restrict__ W3,
          unsigned short* __restrict__ WtBase, float qscale)
{
    __shared__ __align__(16) unsigned short Ts[64][65];
    const int tid = threadIdx.x;
    const int bid = blockIdx.x;
    if (bid < 16384) {
        const int zz = bid >> 13;                       // 0 dec, 1 enc
        const int i = (bid & 8191) * 256 + tid;         // float4 index
        const float* src = zz ? enc : dec;
        unsigned short* dst = zz ? encb : decb;
        float4 v = ((const float4*)src)[i];
        ushort4 o;
        o.x = f2bf(v.x); o.y = f2bf(v.y); o.z = f2bf(v.z); o.w = f2bf(v.w);
        ((ushort4*)dst)[i] = o;
        return;
    }
    const int zid = bid - 16384;                        // 0..1023
    const int z = zid >> 8;                             // weight id 0..3
    const float* W = (z == 0) ? W0 : (z == 1) ? W1 : (z == 2) ? W2 : W3;
    unsigned short* Wt = WtBase + (size_t)z * EMB * EMB;
    const float scale = (z == 0) ? qscale : 1.0f;
    const int n0 = (zid & 15) * 64, k0 = ((zid >> 4) & 15) * 64;
    #pragma unroll
    for (int i = 0; i < 4; ++i) {
        int id = tid + i * 256;
        int r = id >> 4, q = id & 15;
        float4 v = *(const float4*)&W[(size_t)(k0 + r) * EMB + n0 + q * 4];
        Ts[q * 4 + 0][r] = f2bf(v.x * scale);
        Ts[q * 4 + 1][r] = f2bf(v.y * scale);
        Ts[q * 4 + 2][r] = f2bf(v.z * scale);
        Ts[q * 4 + 3][r] = f2bf(v.w * scale);
    }
    __syncthreads();
    #pragma unroll
    for (int i = 0; i < 4; ++i) {
        int id = tid + i * 256;
        int rn = id >> 4, q = id & 15;
        ushort4 o;
        o.x = Ts[rn][q * 4 + 0]; o.y = Ts[rn][q * 4 + 1];
        o.z = Ts[rn][q * 4 + 2]; o.w = Ts[rn][q * 4 + 3];
        *(ushort4*)&Wt[(size_t)(n0 + rn) * EMB + k0 + q * 4] = o;
    }
}

// ---------------------------------------------------------------------------
// GEMM body v2: C[M,N] = A[M,K] @ Bt[N,K]^T. 128x256 tile, BK=32, K=1024
// (KT=32), 512 threads (8 waves, 2M x 4N). THREE-buffer LDS pipeline with
// counted vmcnt (T4): raw s_barrier + inline-asm "s_waitcnt vmcnt(3)" -- loads
// stay in flight across barriers, never drained to 0 inside the loop (the
// vmcnt(0)+barrier drain was the per-K-step stall of the old 2-buffer body).
// Invariant: iter t computes buf t%3 (its loads drained at end of t-1 via
// vmcnt(3)); stages tile t+2 into buf (t+2)%3 (freed by t-1's barrier).
// Output modes as before: BF16R (operand-swapped, 8B stores), F32B (16B
// stores + bias), VTK (V direct to transposed+permuted Vt).
// ---------------------------------------------------------------------------
enum OutKind { OUT_BF16R, OUT_F32B, OUT_VTK };

template<int OK>
__device__ __forceinline__
void gemm_body(const unsigned short* __restrict__ A, const unsigned short* __restrict__ Bt,
               const float* __restrict__ bias, void* __restrict__ Cout,
               int m0, int n0, int N)
{
    constexpr int Kd = 1024;                     // all GEMMs here have K=1024
    __shared__ __align__(16) unsigned short As[3][128 * 32];
    __shared__ __align__(16) unsigned short Bs[3][256 * 32];
    const int tid  = threadIdx.x;
    const int lane = tid & 63, wave = tid >> 6;
    const int g = lane >> 4, c = lane & 15;
    const int wm = (wave >> 2) * 64;             // 2 M-bands of 64
    const int wn = (wave & 3) * 64;              // 4 N-bands of 64

    // staging: 512 threads, A 128x32 (1 issue), B 256x32 (2 issues)
    const int r0 = tid >> 2, s = tid & 3;
    const int sg = s ^ ((r0 + (r0 >> 2)) & 3);   // per-row k-chunk swizzle (period 16)
    const unsigned short* ga  = A  + (size_t)(m0 + r0)       * Kd + sg * 8;
    const unsigned short* gb0 = Bt + (size_t)(n0 + r0)       * Kd + sg * 8;
    const unsigned short* gb1 = Bt + (size_t)(n0 + 128 + r0) * Kd + sg * 8;
    const int loA = tid * 8, loB0 = tid * 8, loB1 = (512 + tid) * 8;

    const int cs = (c + (c >> 2)) & 3;           // read-side un-swizzle

    f32x4 acc[4][4];
    #pragma unroll
    for (int i = 0; i < 4; ++i)
        #pragma unroll
        for (int j = 0; j < 4; ++j) acc[i][j] = (f32x4)0.0f;

    // prologue: stage tiles 0,1 -> bufs 0,1; wait tile 0 (vmcnt(3) leaves
    // tile 1's 3 loads in flight)
    gl_lds16(ga, &As[0][loA]); gl_lds16(gb0, &Bs[0][loB0]); gl_lds16(gb1, &Bs[0][loB1]);
    ga += 32; gb0 += 32; gb1 += 32;
    gl_lds16(ga, &As[1][loA]); gl_lds16(gb0, &Bs[1][loB0]); gl_lds16(gb1, &Bs[1][loB1]);
    ga += 32; gb0 += 32; gb1 += 32;
    asm volatile("s_waitcnt vmcnt(3)" ::: "memory");
    __builtin_amdgcn_s_barrier();

#define GSTEP(T, B, B2)                                                          \
    {                                                                            \
        if ((T) + 2 < 32) {                                                      \
            gl_lds16(ga,  &As[B2][loA]);                                         \
            gl_lds16(gb0, &Bs[B2][loB0]);                                        \
            gl_lds16(gb1, &Bs[B2][loB1]);                                        \
            ga += 32; gb0 += 32; gb1 += 32;                                      \
        }                                                                        \
        bf16x8 af[4], bfv[4];                                                    \
        _Pragma("unroll")                                                        \
        for (int mt = 0; mt < 4; ++mt)                                           \
            af[mt] = *(const bf16x8*)&As[B][(wm + mt * 16 + c) * 32 + (g ^ cs) * 8]; \
        _Pragma("unroll")                                                        \
        for (int nt = 0; nt < 4; ++nt)                                           \
            bfv[nt] = *(const bf16x8*)&Bs[B][(wn + nt * 16 + c) * 32 + (g ^ cs) * 8]; \
        __builtin_amdgcn_s_setprio(1);                                           \
        _Pragma("unroll")                                                        \
        for (int mt = 0; mt < 4; ++mt)                                           \
            _Pragma("unroll")                                                    \
            for (int nt = 0; nt < 4; ++nt) {                                     \
                if (OK == OUT_VTK)                                               \
                    acc[mt][nt] = __builtin_amdgcn_mfma_f32_16x16x32_bf16(af[mt], bfv[nt], acc[mt][nt], 0, 0, 0); \
                else                                                             \
                    acc[mt][nt] = __builtin_amdgcn_mfma_f32_16x16x32_bf16(bfv[nt], af[mt], acc[mt][nt], 0, 0, 0); \
            }                                                                    \
        __builtin_amdgcn_s_setprio(0);                                           \
        if ((T) + 2 < 32)      { asm volatile("s_waitcnt vmcnt(3)" ::: "memory"); } \
        else if ((T) + 1 < 32) { asm volatile("s_waitcnt vmcnt(0)" ::: "memory"); } \
        if ((T) + 1 < 32) __builtin_amdgcn_s_barrier();                          \
    }

    for (int t = 0; t < 30; t += 3) {
        GSTEP(t,     0, 2);
        GSTEP(t + 1, 1, 0);
        GSTEP(t + 2, 2, 1);
    }
    GSTEP(30, 0, 2);
    GSTEP(31, 1, 0);
#undef GSTEP

    if (OK == OUT_VTK) {
        unsigned short* Vt = (unsigned short*)Cout;
        #pragma unroll
        for (int mt = 0; mt < 4; ++mt) {
            int m  = m0 + wm + mt * 16 + 4 * g;          // base of 4-key chunk
            int bb = m >> 11, sl = m & 2047;             // batch, seq within batch
            int sp = (sl & ~31) | (((sl >> 2) & 3) << 3) | (((sl >> 4) & 1) << 2);
            #pragma unroll
            for (int nt = 0; nt < 4; ++nt) {
                int np = n0 + wn + nt * 16 + c;          // h*64+d, 0..1023
                ushort4 o;
                o.x = f2bf(acc[mt][nt][0]); o.y = f2bf(acc[mt][nt][1]);
                o.z = f2bf(acc[mt][nt][2]); o.w = f2bf(acc[mt][nt][3]);
                *(ushort4*)&Vt[((size_t)bb * 1024 + np) * SEQ + sp] = o;
            }
        }
        return;
    }

    if (OK == OUT_BF16R) {
        unsigned short* C = (unsigned short*)Cout;
        #pragma unroll
        for (int mt = 0; mt < 4; ++mt) {
            int m = m0 + wm + mt * 16 + c;
            #pragma unroll
            for (int nt = 0; nt < 4; ++nt) {
                int n = n0 + wn + nt * 16 + 4 * g;
                unsigned u0, u1;
                asm("v_cvt_pk_bf16_f32 %0, %1, %2" : "=v"(u0) : "v"(acc[mt][nt][0]), "v"(acc[mt][nt][1]));
                asm("v_cvt_pk_bf16_f32 %0, %1, %2" : "=v"(u1) : "v"(acc[mt][nt][2]), "v"(acc[mt][nt][3]));
                uint2 st; st.x = u0; st.y = u1;
                *(uint2*)&C[(size_t)m * N + n] = st;     // 8B, n-contiguous
            }
        }
        return;
    }

    // OUT_F32B
    {
        float* C = (float*)Cout;
        #pragma unroll
        for (int nt = 0; nt < 4; ++nt) {
            int n = n0 + wn + nt * 16 + 4 * g;
            float4 bv = *(const float4*)&bias[n];
            #pragma unroll
            for (int mt = 0; mt < 4; ++mt) {
                int m = m0 + wm + mt * 16 + c;
                float4 o;
                o.x = acc[mt][nt][0] + bv.x;
                o.y = acc[mt][nt][1] + bv.y;
                o.z = acc[mt][nt][2] + bv.z;
                o.w = acc[mt][nt][3] + bv.w;
                *(float4*)&C[(size_t)m * N + n] = o;     // 16B, n-contiguous
            }
        }
    }
}

// Fused Q | K | V projections: 64 m-tiles (128 rows) x 12 n-tiles (256 cols)
// = 768 blocks = exactly 3 rounds at 2 blocks/CU. nt 0..3 -> Q, 4..7 -> K,
// 8..11 -> V (direct to transposed+permuted Vt). XCD remap: each XCD owns an
// 8-m-tile band (A 2MB L2-resident), sweeps n outer / m inner so each B-tile
// (0.5MB) is fetched once and reused 8x from L2.
__global__ __launch_bounds__(512, 4)
void proj_fused(const unsigned short* __restrict__ decb, const unsigned short* __restrict__ encb,
                const unsigned short* __restrict__ WtBase,
                unsigned short* __restrict__ Qb, unsigned short* __restrict__ Kb,
                unsigned short* __restrict__ Vtg)
{
    const int fid  = blockIdx.x;                 // 0..767, hw dispatch order
    const int xcd  = fid & 7, idx = fid >> 3;    // idx: 0..95
    const int nt   = idx >> 3;                   // 0..11 (outer)
    const int msub = idx & 7;                    // 0..7  (inner)
    const int m0   = (xcd * 8 + msub) * 128;
    const size_t SML = (size_t)EMB * EMB;
    if (nt < 4) {
        gemm_body<OUT_BF16R>(decb, WtBase, nullptr, Qb, m0, nt * 256, EMB);
    } else if (nt < 8) {
        gemm_body<OUT_BF16R>(encb, WtBase + SML, nullptr, Kb, m0, (nt - 4) * 256, EMB);
    } else {
        gemm_body<OUT_VTK>(encb, WtBase + 2 * SML, nullptr, Vtg, m0, (nt - 8) * 256, 0);
    }
}

// Out projection (fp32 out + bias): 64 m x 4 n = 256 blocks = exactly 1 round.
__global__ __launch_bounds__(512, 4)
void proj_out(const unsigned short* __restrict__ Ob, const unsigned short* __restrict__ WoT,
              const float* __restrict__ bo, float* __restrict__ out)
{
    const int fid  = blockIdx.x;                 // 0..255
    const int xcd  = fid & 7, idx = fid >> 3;    // idx: 0..31
    const int nt   = idx >> 3;                   // 0..3
    const int msub = idx & 7;
    const int m0   = (xcd * 8 + msub) * 128;
    gemm_body<OUT_F32B>(Ob, WoT, bo, out, m0, nt * 256, EMB);
}

// ---------------------------------------------------------------------------
// MFMA flash attention, S^T formulation, static max folded into MFMA C-init.
// P stays in registers (permuted k-map matching Vt); l = P @ ones on the MFMA
// pipe. QBLK = 64: 2048 blocks, 5 resident/CU, staggered phases de-lockstep
// VALU and MFMA bursts across blocks. UNCHANGED (stable 88 us, ~90% issue).
// ---------------------------------------------------------------------------
__global__ __launch_bounds__(256)
void attn(const unsigned short* __restrict__ Q, const unsigned short* __restrict__ K,
          const unsigned short* __restrict__ Vt, unsigned short* __restrict__ O)
{
    __shared__ __align__(16) unsigned short Ks[2][64 * 64];  // [key][d], seg^(row&7)
    __shared__ __align__(16) unsigned short Vs[2][64 * 64];  // [d][key], seg^(row&7)

    const int tid  = threadIdx.x;
    const int lane = tid & 63, wave = tid >> 6;
    const int g = lane >> 4, c = lane & 15, c7 = c & 7;

    // XCD-aware bijective remap of the 2048 blocks (32 q-tiles x 64 bh)
    const int fid  = blockIdx.y * 32 + blockIdx.x;  // hw dispatch order (x fastest)
    const int xcd  = fid & 7, idx = fid >> 3;       // idx: 0..255 within XCD
    const int bh   = (xcd << 3) | (idx >> 5);       // 8 heads per XCD
    const int qblk = idx & 31;
    const int b = bh >> 4, h = bh & 15;
    const int qw = qblk * 64 + wave * 16;

    const unsigned short* Qp0 = Q + (size_t)(b * SEQ + qw + c) * EMB + h * HD;
    bf16x8 qb[2];
    qb[0] = *(const bf16x8*)(Qp0 + g * 8);
    qb[1] = *(const bf16x8*)(Qp0 + 32 + g * 8);

    const int r0 = tid >> 3, s8 = tid & 7;
    const int sg = s8 ^ (r0 & 7);
    const unsigned short* gK0 = K + ((size_t)b * SEQ + r0) * EMB + h * HD + sg * 8;
    const unsigned short* gK1 = gK0 + (size_t)32 * EMB;
    const unsigned short* gV0 = Vt + (size_t)bh * HD * SEQ + (size_t)r0 * SEQ + sg * 8;
    const unsigned short* gV1 = gV0 + (size_t)32 * SEQ;
    const int lo0 = tid * 8, lo1 = (256 + tid) * 8;

    f32x4 oac[4];
    #pragma unroll
    for (int dt = 0; dt < 4; ++dt) oac[dt] = (f32x4)0.0f;
    f32x4 lacc = (f32x4)0.0f;
    const f32x4 minit = {-SOFTMAX_C, -SOFTMAX_C, -SOFTMAX_C, -SOFTMAX_C};
    const short onebf = (short)0x3F80;               // bf16 1.0
    const bf16x8 vones = {onebf, onebf, onebf, onebf, onebf, onebf, onebf, onebf};

    // prologue: tile 0 -> buf0
    gl_lds16(gK0, &Ks[0][lo0]); gl_lds16(gK1, &Ks[0][lo1]);
    gl_lds16(gV0, &Vs[0][lo0]); gl_lds16(gV1, &Vs[0][lo1]);
    gK0 += (size_t)64 * EMB; gK1 += (size_t)64 * EMB; gV0 += 64; gV1 += 64;
    __syncthreads();

    constexpr int T = SEQ / 64;                  // 32, even
    for (int t = 0; t < T; t += 2) {
        #pragma unroll
        for (int h2 = 0; h2 < 2; ++h2) {         // h2 = buffer parity (constant)
            const int tt = t + h2;
            if (tt + 1 < T) {                    // issue next K/V tile early
                gl_lds16(gK0, &Ks[h2 ^ 1][lo0]); gl_lds16(gK1, &Ks[h2 ^ 1][lo1]);
                gl_lds16(gV0, &Vs[h2 ^ 1][lo0]); gl_lds16(gV1, &Vs[h2 ^ 1][lo1]);
                gK0 += (size_t)64 * EMB; gK1 += (size_t)64 * EMB;
                gV0 += 64;               gV1 += 64;
            }

            // S^T = K Q^T, C-init = -C (softmax shift folded in)
            f32x4 st[4];
            __builtin_amdgcn_s_setprio(1);
            #pragma unroll
            for (int kt = 0; kt < 4; ++kt) {
                bf16x8 ka0 = *(const bf16x8*)&Ks[h2][(kt * 16 + c) * 64 + (g ^ c7) * 8];
                bf16x8 ka1 = *(const bf16x8*)&Ks[h2][(kt * 16 + c) * 64 + ((4 + g) ^ c7) * 8];
                st[kt] = __builtin_amdgcn_mfma_f32_16x16x32_bf16(ka0, qb[0], minit, 0, 0, 0);
                st[kt] = __builtin_amdgcn_mfma_f32_16x16x32_bf16(ka1, qb[1], st[kt], 0, 0, 0);
            }
            __builtin_amdgcn_s_setprio(0);

            // p = exp2(st); pack in-register (v_cvt_pk_bf16_f32)
            bf16x8 pa[2];
            {
                unsigned uu[8];
                #pragma unroll
                for (int kt = 0; kt < 4; ++kt) {
                    float p0 = __builtin_amdgcn_exp2f(st[kt][0]);
                    float p1 = __builtin_amdgcn_exp2f(st[kt][1]);
                    float p2 = __builtin_amdgcn_exp2f(st[kt][2]);
                    float p3 = __builtin_amdgcn_exp2f(st[kt][3]);
                    asm("v_cvt_pk_bf16_f32 %0, %1, %2" : "=v"(uu[2 * kt])     : "v"(p0), "v"(p1));
                    asm("v_cvt_pk_bf16_f32 %0, %1, %2" : "=v"(uu[2 * kt + 1]) : "v"(p2), "v"(p3));
                }
                u32x4v w0 = {uu[0], uu[1], uu[2], uu[3]};   // keys (kt0,kt1) -> MFMA k 0..31
                u32x4v w1 = {uu[4], uu[5], uu[6], uu[7]};   // keys (kt2,kt3) -> MFMA k 32..63
                pa[0] = __builtin_bit_cast(bf16x8, w0);
                pa[1] = __builtin_bit_cast(bf16x8, w1);
            }

            // O += P V; l += P @ ones (MFMA pipe, same A-fragments)
            __builtin_amdgcn_s_setprio(1);
            #pragma unroll
            for (int dt = 0; dt < 4; ++dt) {
                bf16x8 vb0 = *(const bf16x8*)&Vs[h2][(dt * 16 + c) * 64 + (g ^ c7) * 8];
                bf16x8 vb1 = *(const bf16x8*)&Vs[h2][(dt * 16 + c) * 64 + ((4 + g) ^ c7) * 8];
                oac[dt] = __builtin_amdgcn_mfma_f32_16x16x32_bf16(pa[0], vb0, oac[dt], 0, 0, 0);
                oac[dt] = __builtin_amdgcn_mfma_f32_16x16x32_bf16(pa[1], vb1, oac[dt], 0, 0, 0);
            }
            lacc = __builtin_amdgcn_mfma_f32_16x16x32_bf16(pa[0], vones, lacc, 0, 0, 0);
            lacc = __builtin_amdgcn_mfma_f32_16x16x32_bf16(pa[1], vones, lacc, 0, 0, 0);
            __builtin_amdgcn_s_setprio(0);

            __syncthreads();                     // drain (hidden) + buffer handoff
        }
    }

    // lacc[r] = l for q-row (qw + 4g + r) — same row map as oac.
    unsigned short* Op = O + (size_t)(b * SEQ + qw) * EMB + h * HD;
    #pragma unroll
    for (int r = 0; r < 4; ++r) {
        float linv = 1.0f / lacc[r];
        #pragma unroll
        for (int dt = 0; dt < 4; ++dt)
            Op[(size_t)(4 * g + r) * EMB + dt * 16 + c] = f2bf(oac[dt][r] * linv);
    }
}

} // anonymous namespace

extern "C" void kernel_launch(void* const* d_in, const int* in_sizes, int n_in,
                              void* d_out, int out_size, void* d_ws, size_t ws_size,
                              hipStream_t stream)
{
    const float* dec = (const float*)d_in[0];
    const float* enc = (const float*)d_in[1];
    const float* Wq  = (const float*)d_in[2];
    const float* Wk  = (const float*)d_in[3];
    const float* Wv  = (const float*)d_in[4];
    const float* Wo  = (const float*)d_in[5];
    const float* bo  = (const float*)d_in[6];
    float* out = (float*)d_out;

    const size_t BIG = (size_t)MTOT * EMB;     // 8M elems
    const size_t SML = (size_t)EMB * EMB;      // 1M elems
    unsigned short* decb = (unsigned short*)d_ws;
    unsigned short* encb = decb + BIG;
    unsigned short* WqT  = encb + BIG;         // Wq,Wk,Wv,Wo transposed, contiguous
    unsigned short* WoT  = WqT + 3 * SML;
    unsigned short* Qb   = WqT + 4 * SML;
    unsigned short* Kb   = Qb + BIG;           // [8192][1024] K only
    unsigned short* Vtg  = Kb + BIG;           // [4096][2048] transposed+permuted V
    unsigned short* Ob   = Vtg + BIG;          // total 104 MB

    // conv (dec/enc) + all weight transposes, flat grid, no idle blocks
    prep<<<dim3(16384 + 1024), dim3(256), 0, stream>>>(
        dec, enc, decb, encb, Wq, Wk, Wv, Wo, WqT, 0.125f * LOG2E);

    // fused Q | K | V projections: 768 blocks of 512 threads (3 exact rounds)
    proj_fused<<<dim3(768), dim3(512), 0, stream>>>(decb, encb, WqT, Qb, Kb, Vtg);

    // QBLK=64: 32 q-tiles x 64 bh = 2048 blocks, 5 resident blocks/CU
    attn<<<dim3(SEQ / 64, BATCH * NH), dim3(256), 0, stream>>>(Qb, Kb, Vtg, Ob);

    // 256 blocks of 512 threads (1 exact round)
    proj_out<<<dim3(256), dim3(512), 0, stream>>>(Ob, WoT, bo, out);
}

// Round 8
// 302.291 us; speedup vs baseline: 1.0599x; 1.0599x over previous
//
#include <hip/hip_runtime.h>
#include <hip/hip_bf16.h>

namespace {

typedef __attribute__((ext_vector_type(8))) short bf16x8;   // 8 bf16 = 4 VGPRs
typedef __attribute__((ext_vector_type(4))) float f32x4;
typedef __attribute__((ext_vector_type(4))) unsigned u32x4v;

constexpr int BATCH = 4;
constexpr int SEQ   = 2048;
constexpr int EMB   = 1024;
constexpr int NH    = 16;
constexpr int HD    = 64;
constexpr int MTOT  = BATCH * SEQ;           // 8192
constexpr float LOG2E = 1.44269504088896f;
constexpr float SOFTMAX_C = 16.0f;           // static max substitute (log2 units)

__device__ __forceinline__ unsigned short f2bf(float x) {
    unsigned int u = __float_as_uint(x);
    u += 0x7fffu + ((u >> 16) & 1u);         // round-to-nearest-even
    return (unsigned short)(u >> 16);
}

// async global->LDS, 16B per lane; LDS dest must be wave-uniform base + lane*16
__device__ __forceinline__ void gl_lds16(const void* g, void* l) {
    __builtin_amdgcn_global_load_lds(
        (const __attribute__((address_space(1))) unsigned int*)g,
        (__attribute__((address_space(3))) unsigned int*)l, 16, 0, 0);
}

// ---------------------------------------------------------------------------
// Fused preprocessing, flat 1D grid (no idle blocks):
//   bid <  16384 : fp32->bf16 conv of dec (bid<8192) / enc
//   bid >= 16384 : 1024 weight-transpose blocks (4 weights x 16x16 tiles)
// ---------------------------------------------------------------------------
__global__ __launch_bounds__(256)
void prep(const float* __restrict__ dec, const float* __restrict__ enc,
          unsigned short* __restrict__ decb, unsigned short* __restrict__ encb,
          const float* __restrict__ W0, const float* __restrict__ W1,
          const float* __restrict__ W2, const float* __restrict__ W3,
          unsigned short* __restrict__ WtBase, float qscale)
{
    __shared__ __align__(16) unsigned short Ts[64][65];
    const int tid = threadIdx.x;
    const int bid = blockIdx.x;
    if (bid < 16384) {
        const int zz = bid >> 13;                       // 0 dec, 1 enc
        const int i = (bid & 8191) * 256 + tid;         // float4 index
        const float* src = zz ? enc : dec;
        unsigned short* dst = zz ? encb : decb;
        float4 v = ((const float4*)src)[i];
        ushort4 o;
        o.x = f2bf(v.x); o.y = f2bf(v.y); o.z = f2bf(v.z); o.w = f2bf(v.w);
        ((ushort4*)dst)[i] = o;
        return;
    }
    const int zid = bid - 16384;                        // 0..1023
    const int z = zid >> 8;                             // weight id 0..3
    const float* W = (z == 0) ? W0 : (z == 1) ? W1 : (z == 2) ? W2 : W3;
    unsigned short* Wt = WtBase + (size_t)z * EMB * EMB;
    const float scale = (z == 0) ? qscale : 1.0f;
    const int n0 = (zid & 15) * 64, k0 = ((zid >> 4) & 15) * 64;
    #pragma unroll
    for (int i = 0; i < 4; ++i) {
        int id = tid + i * 256;
        int r = id >> 4, q = id & 15;
        float4 v = *(const float4*)&W[(size_t)(k0 + r) * EMB + n0 + q * 4];
        Ts[q * 4 + 0][r] = f2bf(v.x * scale);
        Ts[q * 4 + 1][r] = f2bf(v.y * scale);
        Ts[q * 4 + 2][r] = f2bf(v.z * scale);
        Ts[q * 4 + 3][r] = f2bf(v.w * scale);
    }
    __syncthreads();
    #pragma unroll
    for (int i = 0; i < 4; ++i) {
        int id = tid + i * 256;
        int rn = id >> 4, q = id & 15;
        ushort4 o;
        o.x = Ts[rn][q * 4 + 0]; o.y = Ts[rn][q * 4 + 1];
        o.z = Ts[rn][q * 4 + 2]; o.w = Ts[rn][q * 4 + 3];
        *(ushort4*)&Wt[(size_t)(n0 + rn) * EMB + k0 + q * 4] = o;
    }
}

// ---------------------------------------------------------------------------
// Pipelined GEMM body (round-6 proven structure): C[M,N] = A[M,K] @ Bt[N,K]^T.
// 128x128 tile, BK=32, 256 threads, double-buffered LDS + global_load_lds.
// LDS IS PASSED IN by the kernel (single 32KB allocation shared by ALL
// template instantiations -- previously each instantiation carried its own
// __shared__ arrays and the compiler summed them: proj_fused ran at 64KB ->
// 2 blocks/CU. Single allocation -> 5 blocks/CU, 20 waves/CU).
// lds layout: As = lds[buf*4096 + .], Bs = lds[8192 + buf*4096 + .]
// Output modes: BF16R (operand-swapped, 8B stores), F32B (16B stores + bias),
// VTK (V direct to transposed+permuted Vt, unswapped operands, 8B stores).
// ---------------------------------------------------------------------------
enum OutKind { OUT_BF16R, OUT_F32B, OUT_VTK };

template<int OK>
__device__ __forceinline__
void gemm_body(unsigned short* lds,
               const unsigned short* __restrict__ A, const unsigned short* __restrict__ Bt,
               const float* __restrict__ bias, void* __restrict__ Cout,
               int m0, int n0, int N, int Kd)
{
    const int tid  = threadIdx.x;
    const int lane = tid & 63, wave = tid >> 6;
    const int g = lane >> 4, c = lane & 15;
    const int wm = (wave & 1) * 64, wn = (wave >> 1) * 64;

    const int r0 = tid >> 2, s = tid & 3;
    const int sg = s ^ ((r0 + (r0 >> 2)) & 3);
    const unsigned short* ga0 = A  + (size_t)(m0 + r0)      * Kd + sg * 8;
    const unsigned short* ga1 = A  + (size_t)(m0 + r0 + 64) * Kd + sg * 8;
    const unsigned short* gb0 = Bt + (size_t)(n0 + r0)      * Kd + sg * 8;
    const unsigned short* gb1 = Bt + (size_t)(n0 + r0 + 64) * Kd + sg * 8;
    const int lo0 = tid * 8, lo1 = (256 + tid) * 8;

    const int cs = (c + (c >> 2)) & 3;

    f32x4 acc[4][4];
    #pragma unroll
    for (int i = 0; i < 4; ++i)
        #pragma unroll
        for (int j = 0; j < 4; ++j) acc[i][j] = (f32x4)0.0f;

    // prologue: tile 0 -> buf0
    gl_lds16(ga0, &lds[lo0]);        gl_lds16(ga1, &lds[lo1]);
    gl_lds16(gb0, &lds[8192 + lo0]); gl_lds16(gb1, &lds[8192 + lo1]);
    ga0 += 32; ga1 += 32; gb0 += 32; gb1 += 32;
    __syncthreads();

    const int KT = Kd / 32;                      // even
    for (int kt = 0; kt < KT; kt += 2) {
        #pragma unroll
        for (int h2 = 0; h2 < 2; ++h2) {         // h2 = buffer parity (constant)
            const int k = kt + h2;
            const int bcur = h2 * 4096, bnxt = (h2 ^ 1) * 4096;
            if (k + 1 < KT) {                    // issue next tile early (async)
                gl_lds16(ga0, &lds[bnxt + lo0]);        gl_lds16(ga1, &lds[bnxt + lo1]);
                gl_lds16(gb0, &lds[8192 + bnxt + lo0]); gl_lds16(gb1, &lds[8192 + bnxt + lo1]);
                ga0 += 32; ga1 += 32; gb0 += 32; gb1 += 32;
            }
            bf16x8 af[4], bfr[4];
            #pragma unroll
            for (int mt = 0; mt < 4; ++mt)
                af[mt]  = *(const bf16x8*)&lds[bcur + (wm + mt * 16 + c) * 32 + (g ^ cs) * 8];
            #pragma unroll
            for (int nt = 0; nt < 4; ++nt)
                bfr[nt] = *(const bf16x8*)&lds[8192 + bcur + (wn + nt * 16 + c) * 32 + (g ^ cs) * 8];
            #pragma unroll
            for (int mt = 0; mt < 4; ++mt)
                #pragma unroll
                for (int nt = 0; nt < 4; ++nt) {
                    if (OK == OUT_VTK)           // rows = m (4g+r), cols = n (c)
                        acc[mt][nt] = __builtin_amdgcn_mfma_f32_16x16x32_bf16(af[mt], bfr[nt], acc[mt][nt], 0, 0, 0);
                    else                         // C^T frag: rows = n (4g+r), cols = m (c)
                        acc[mt][nt] = __builtin_amdgcn_mfma_f32_16x16x32_bf16(bfr[nt], af[mt], acc[mt][nt], 0, 0, 0);
                }
            __syncthreads();                     // drain lands post-compute
        }
    }

    if (OK == OUT_VTK) {
        unsigned short* Vt = (unsigned short*)Cout;
        #pragma unroll
        for (int mt = 0; mt < 4; ++mt) {
            int m  = m0 + wm + mt * 16 + 4 * g;          // base of 4-key chunk
            int bb = m >> 11, sl = m & 2047;             // batch, seq within batch
            int sp = (sl & ~31) | (((sl >> 2) & 3) << 3) | (((sl >> 4) & 1) << 2);
            #pragma unroll
            for (int nt = 0; nt < 4; ++nt) {
                int np = n0 + wn + nt * 16 + c;          // h*64+d, 0..1023
                ushort4 o;
                o.x = f2bf(acc[mt][nt][0]); o.y = f2bf(acc[mt][nt][1]);
                o.z = f2bf(acc[mt][nt][2]); o.w = f2bf(acc[mt][nt][3]);
                *(ushort4*)&Vt[((size_t)bb * 1024 + np) * SEQ + sp] = o;
            }
        }
        return;
    }

    if (OK == OUT_BF16R) {
        unsigned short* C = (unsigned short*)Cout;
        #pragma unroll
        for (int mt = 0; mt < 4; ++mt) {
            int m = m0 + wm + mt * 16 + c;
            #pragma unroll
            for (int nt = 0; nt < 4; ++nt) {
                int n = n0 + wn + nt * 16 + 4 * g;
                unsigned u0, u1;
                asm("v_cvt_pk_bf16_f32 %0, %1, %2" : "=v"(u0) : "v"(acc[mt][nt][0]), "v"(acc[mt][nt][1]));
                asm("v_cvt_pk_bf16_f32 %0, %1, %2" : "=v"(u1) : "v"(acc[mt][nt][2]), "v"(acc[mt][nt][3]));
                uint2 st; st.x = u0; st.y = u1;
                *(uint2*)&C[(size_t)m * N + n] = st;     // 8B, n-contiguous
            }
        }
        return;
    }

    // OUT_F32B
    {
        float* C = (float*)Cout;
        #pragma unroll
        for (int nt = 0; nt < 4; ++nt) {
            int n = n0 + wn + nt * 16 + 4 * g;
            float4 bv = *(const float4*)&bias[n];
            #pragma unroll
            for (int mt = 0; mt < 4; ++mt) {
                int m = m0 + wm + mt * 16 + c;
                float4 o;
                o.x = acc[mt][nt][0] + bv.x;
                o.y = acc[mt][nt][1] + bv.y;
                o.z = acc[mt][nt][2] + bv.z;
                o.w = acc[mt][nt][3] + bv.w;
                *(float4*)&C[(size_t)m * N + n] = o;     // 16B, n-contiguous
            }
        }
    }
}

// Fused Q | K | V projections: 24 n-tiles x 64 m-tiles = 1536 blocks.
// nt 0..7 -> Q; 8..15 -> K (compact Kb); 16..23 -> V direct to transposed+
// permuted Vt. XCD remap: each XCD owns a contiguous band of 8 m-tiles.
// SINGLE shared-LDS allocation passed to both instantiations (32KB total).
__global__ __launch_bounds__(256)
void proj_fused(const unsigned short* __restrict__ decb, const unsigned short* __restrict__ encb,
                const unsigned short* __restrict__ WtBase,
                unsigned short* __restrict__ Qb, unsigned short* __restrict__ Kb,
                unsigned short* __restrict__ Vtg)
{
    __shared__ __align__(16) unsigned short lds[16384];   // 32 KB, shared by all paths
    const int fid = blockIdx.y * 24 + blockIdx.x;   // 0..1535, hw dispatch order
    const int xcd = fid & 7, idx = fid >> 3;        // idx: 0..191
    const int mt  = (xcd << 3) | (idx / 24);        // 0..63  (8 m-tiles per XCD)
    const int nt  = idx % 24;
    const int m0  = mt * 128;
    const size_t SML = (size_t)EMB * EMB;
    if (nt < 8) {
        gemm_body<OUT_BF16R>(lds, decb, WtBase, nullptr, Qb, m0, nt * 128, EMB, EMB);
    } else if (nt < 16) {
        gemm_body<OUT_BF16R>(lds, encb, WtBase + SML, nullptr, Kb,
                             m0, (nt - 8) * 128, EMB, EMB);
    } else {
        gemm_body<OUT_VTK>(lds, encb, WtBase + 2 * SML, nullptr, Vtg,
                           m0, (nt - 16) * 128, 0, EMB);
    }
}

// Out projection (fp32 out + bias), same XCD-band remap (512 blocks).
__global__ __launch_bounds__(256)
void proj_out(const unsigned short* __restrict__ Ob, const unsigned short* __restrict__ WoT,
              const float* __restrict__ bo, float* __restrict__ out)
{
    __shared__ __align__(16) unsigned short lds[16384];   // 32 KB
    const int fid = blockIdx.y * 8 + blockIdx.x;    // 0..511
    const int xcd = fid & 7, idx = fid >> 3;        // idx: 0..63
    const int mt  = (xcd << 3) | (idx >> 3);
    const int nt  = idx & 7;
    gemm_body<OUT_F32B>(lds, Ob, WoT, bo, out, mt * 128, nt * 128, EMB, EMB);
}

// ---------------------------------------------------------------------------
// MFMA flash attention, S^T formulation, static max folded into MFMA C-init.
// P stays in registers (permuted k-map matching Vt); l = P @ ones on the MFMA
// pipe. QBLK = 64: 2048 blocks, 5 resident/CU, staggered phases de-lockstep
// VALU and MFMA bursts across blocks. UNCHANGED (stable ~87.5 us).
// ---------------------------------------------------------------------------
__global__ __launch_bounds__(256)
void attn(const unsigned short* __restrict__ Q, const unsigned short* __restrict__ K,
          const unsigned short* __restrict__ Vt, unsigned short* __restrict__ O)
{
    __shared__ __align__(16) unsigned short Ks[2][64 * 64];  // [key][d], seg^(row&7)
    __shared__ __align__(16) unsigned short Vs[2][64 * 64];  // [d][key], seg^(row&7)

    const int tid  = threadIdx.x;
    const int lane = tid & 63, wave = tid >> 6;
    const int g = lane >> 4, c = lane & 15, c7 = c & 7;

    // XCD-aware bijective remap of the 2048 blocks (32 q-tiles x 64 bh)
    const int fid  = blockIdx.y * 32 + blockIdx.x;  // hw dispatch order (x fastest)
    const int xcd  = fid & 7, idx = fid >> 3;       // idx: 0..255 within XCD
    const int bh   = (xcd << 3) | (idx >> 5);       // 8 heads per XCD
    const int qblk = idx & 31;
    const int b = bh >> 4, h = bh & 15;
    const int qw = qblk * 64 + wave * 16;

    const unsigned short* Qp0 = Q + (size_t)(b * SEQ + qw + c) * EMB + h * HD;
    bf16x8 qb[2];
    qb[0] = *(const bf16x8*)(Qp0 + g * 8);
    qb[1] = *(const bf16x8*)(Qp0 + 32 + g * 8);

    const int r0 = tid >> 3, s8 = tid & 7;
    const int sg = s8 ^ (r0 & 7);
    const unsigned short* gK0 = K + ((size_t)b * SEQ + r0) * EMB + h * HD + sg * 8;
    const unsigned short* gK1 = gK0 + (size_t)32 * EMB;
    const unsigned short* gV0 = Vt + (size_t)bh * HD * SEQ + (size_t)r0 * SEQ + sg * 8;
    const unsigned short* gV1 = gV0 + (size_t)32 * SEQ;
    const int lo0 = tid * 8, lo1 = (256 + tid) * 8;

    f32x4 oac[4];
    #pragma unroll
    for (int dt = 0; dt < 4; ++dt) oac[dt] = (f32x4)0.0f;
    f32x4 lacc = (f32x4)0.0f;
    const f32x4 minit = {-SOFTMAX_C, -SOFTMAX_C, -SOFTMAX_C, -SOFTMAX_C};
    const short onebf = (short)0x3F80;               // bf16 1.0
    const bf16x8 vones = {onebf, onebf, onebf, onebf, onebf, onebf, onebf, onebf};

    // prologue: tile 0 -> buf0
    gl_lds16(gK0, &Ks[0][lo0]); gl_lds16(gK1, &Ks[0][lo1]);
    gl_lds16(gV0, &Vs[0][lo0]); gl_lds16(gV1, &Vs[0][lo1]);
    gK0 += (size_t)64 * EMB; gK1 += (size_t)64 * EMB; gV0 += 64; gV1 += 64;
    __syncthreads();

    constexpr int T = SEQ / 64;                  // 32, even
    for (int t = 0; t < T; t += 2) {
        #pragma unroll
        for (int h2 = 0; h2 < 2; ++h2) {         // h2 = buffer parity (constant)
            const int tt = t + h2;
            if (tt + 1 < T) {                    // issue next K/V tile early
                gl_lds16(gK0, &Ks[h2 ^ 1][lo0]); gl_lds16(gK1, &Ks[h2 ^ 1][lo1]);
                gl_lds16(gV0, &Vs[h2 ^ 1][lo0]); gl_lds16(gV1, &Vs[h2 ^ 1][lo1]);
                gK0 += (size_t)64 * EMB; gK1 += (size_t)64 * EMB;
                gV0 += 64;               gV1 += 64;
            }

            // S^T = K Q^T, C-init = -C (softmax shift folded in)
            f32x4 st[4];
            __builtin_amdgcn_s_setprio(1);
            #pragma unroll
            for (int kt = 0; kt < 4; ++kt) {
                bf16x8 ka0 = *(const bf16x8*)&Ks[h2][(kt * 16 + c) * 64 + (g ^ c7) * 8];
                bf16x8 ka1 = *(const bf16x8*)&Ks[h2][(kt * 16 + c) * 64 + ((4 + g) ^ c7) * 8];
                st[kt] = __builtin_amdgcn_mfma_f32_16x16x32_bf16(ka0, qb[0], minit, 0, 0, 0);
                st[kt] = __builtin_amdgcn_mfma_f32_16x16x32_bf16(ka1, qb[1], st[kt], 0, 0, 0);
            }
            __builtin_amdgcn_s_setprio(0);

            // p = exp2(st); pack in-register (v_cvt_pk_bf16_f32)
            bf16x8 pa[2];
            {
                unsigned uu[8];
                #pragma unroll
                for (int kt = 0; kt < 4; ++kt) {
                    float p0 = __builtin_amdgcn_exp2f(st[kt][0]);
                    float p1 = __builtin_amdgcn_exp2f(st[kt][1]);
                    float p2 = __builtin_amdgcn_exp2f(st[kt][2]);
                    float p3 = __builtin_amdgcn_exp2f(st[kt][3]);
                    asm("v_cvt_pk_bf16_f32 %0, %1, %2" : "=v"(uu[2 * kt])     : "v"(p0), "v"(p1));
                    asm("v_cvt_pk_bf16_f32 %0, %1, %2" : "=v"(uu[2 * kt + 1]) : "v"(p2), "v"(p3));
                }
                u32x4v w0 = {uu[0], uu[1], uu[2], uu[3]};   // keys (kt0,kt1) -> MFMA k 0..31
                u32x4v w1 = {uu[4], uu[5], uu[6], uu[7]};   // keys (kt2,kt3) -> MFMA k 32..63
                pa[0] = __builtin_bit_cast(bf16x8, w0);
                pa[1] = __builtin_bit_cast(bf16x8, w1);
            }

            // O += P V; l += P @ ones (MFMA pipe, same A-fragments)
            __builtin_amdgcn_s_setprio(1);
            #pragma unroll
            for (int dt = 0; dt < 4; ++dt) {
                bf16x8 vb0 = *(const bf16x8*)&Vs[h2][(dt * 16 + c) * 64 + (g ^ c7) * 8];
                bf16x8 vb1 = *(const bf16x8*)&Vs[h2][(dt * 16 + c) * 64 + ((4 + g) ^ c7) * 8];
                oac[dt] = __builtin_amdgcn_mfma_f32_16x16x32_bf16(pa[0], vb0, oac[dt], 0, 0, 0);
                oac[dt] = __builtin_amdgcn_mfma_f32_16x16x32_bf16(pa[1], vb1, oac[dt], 0, 0, 0);
            }
            lacc = __builtin_amdgcn_mfma_f32_16x16x32_bf16(pa[0], vones, lacc, 0, 0, 0);
            lacc = __builtin_amdgcn_mfma_f32_16x16x32_bf16(pa[1], vones, lacc, 0, 0, 0);
            __builtin_amdgcn_s_setprio(0);

            __syncthreads();                     // drain (hidden) + buffer handoff
        }
    }

    // lacc[r] = l for q-row (qw + 4g + r) — same row map as oac.
    unsigned short* Op = O + (size_t)(b * SEQ + qw) * EMB + h * HD;
    #pragma unroll
    for (int r = 0; r < 4; ++r) {
        float linv = 1.0f / lacc[r];
        #pragma unroll
        for (int dt = 0; dt < 4; ++dt)
            Op[(size_t)(4 * g + r) * EMB + dt * 16 + c] = f2bf(oac[dt][r] * linv);
    }
}

} // anonymous namespace

extern "C" void kernel_launch(void* const* d_in, const int* in_sizes, int n_in,
                              void* d_out, int out_size, void* d_ws, size_t ws_size,
                              hipStream_t stream)
{
    const float* dec = (const float*)d_in[0];
    const float* enc = (const float*)d_in[1];
    const float* Wq  = (const float*)d_in[2];
    const float* Wk  = (const float*)d_in[3];
    const float* Wv  = (const float*)d_in[4];
    const float* Wo  = (const float*)d_in[5];
    const float* bo  = (const float*)d_in[6];
    float* out = (float*)d_out;

    const size_t BIG = (size_t)MTOT * EMB;     // 8M elems
    const size_t SML = (size_t)EMB * EMB;      // 1M elems
    unsigned short* decb = (unsigned short*)d_ws;
    unsigned short* encb = decb + BIG;
    unsigned short* WqT  = encb + BIG;         // Wq,Wk,Wv,Wo transposed, contiguous
    unsigned short* WoT  = WqT + 3 * SML;
    unsigned short* Qb   = WqT + 4 * SML;
    unsigned short* Kb   = Qb + BIG;           // [8192][1024] K only
    unsigned short* Vtg  = Kb + BIG;           // [4096][2048] transposed+permuted V
    unsigned short* Ob   = Vtg + BIG;          // total 104 MB

    dim3 blk(256);

    // conv (dec/enc) + all weight transposes, flat grid, no idle blocks
    prep<<<dim3(16384 + 1024), blk, 0, stream>>>(
        dec, enc, decb, encb, Wq, Wk, Wv, Wo, WqT, 0.125f * LOG2E);

    // fused Q | K | V projections (single 32KB LDS -> 5 blocks/CU)
    proj_fused<<<dim3(24, MTOT / 128), blk, 0, stream>>>(decb, encb, WqT, Qb, Kb, Vtg);

    // QBLK=64: 32 q-tiles x 64 bh = 2048 blocks, 5 resident blocks/CU
    attn<<<dim3(SEQ / 64, BATCH * NH), blk, 0, stream>>>(Qb, Kb, Vtg, Ob);

    proj_out<<<dim3(EMB / 128, MTOT / 128), blk, 0, stream>>>(Ob, WoT, bo, out);
}